// Round 1
// baseline (656.453 us; speedup 1.0000x reference)
//
#include <hip/hip_runtime.h>
#include <hip/hip_bf16.h>
#include <stdint.h>
#include <stddef.h>

// ---------------------------------------------------------------------------
// InteractionPredictionHead: edge MLP over a graph.
//   logits[e] = relu(relu([src|dst|attr]@W1+b1)@W2+b2 ... ) per reference.
// Key algebraic rewrite: feats@W1 = P[src] + Q[dst] + attr@W1c + b1, with
//   P = emb@W1[0:256,:], Q = emb@W1[256:512,:]  (per-NODE, 50k rows not 300k)
// Kernels: prep_pack (weight bf16 images into ws), gemm1 (PQ), fused (rest).
// MFMA: v_mfma_f32_32x32x16_bf16, swapped operands (D = W^T * act^T) so that
//   B-frag = lane-local contiguous activation octets (no LDS transpose for h1)
//   A-frag (weights) row-major [out][k] contiguous 16B reads.
// Verified layouts used (guide m74/m101): C/D col=lane&31,
//   row=(reg&3)+8*(reg>>2)+4*(lane>>5); A row=lane&31,k=(lane>>5)*8+j; B mirrors.
// ---------------------------------------------------------------------------

#define NN 50000
#define NE 300000

using bf16x8 = __attribute__((ext_vector_type(8))) short;
using f32x16 = __attribute__((ext_vector_type(16))) float;
using f32x4  = __attribute__((ext_vector_type(4))) float;
using u16x4  = __attribute__((ext_vector_type(4))) unsigned short;

// ---- ws layout (bytes, all 16B aligned) ----
#define OFF_PQ   0ULL
#define SZ_PQ    (50000ULL*512ULL*2ULL)          // PQ bf16 [n][512]  (51.2 MB)
#define OFF_W1   (OFF_PQ + SZ_PQ)                // W1ab^T bf16 [512 out][256 k]
#define SZ_W1    (512ULL*256ULL*2ULL)
#define OFF_W1C  (OFF_W1 + SZ_W1)                // W1c f32 [3][256]
#define SZ_W1C   (3ULL*256ULL*4ULL)
#define OFF_W2   (OFF_W1C + SZ_W1C)              // 4 chunks [128 out][72 k] bf16
#define SZ_W2    (4ULL*128ULL*72ULL*2ULL)
#define OFF_W3   (OFF_W2 + SZ_W2)                // 2 chunks [64][72]
#define SZ_W3    (2ULL*64ULL*72ULL*2ULL)
#define OFF_W4   (OFF_W3 + SZ_W3)                // 1 chunk [32][72]
#define SZ_W4    (32ULL*72ULL*2ULL)
#define OFF_FLAG (OFF_W4 + SZ_W4)
#define WS_NEED  (OFF_FLAG + 16ULL)

__device__ __forceinline__ unsigned short f2bf(float x){
  unsigned u = __float_as_uint(x);
  unsigned r = 0x7FFFu + ((u >> 16) & 1u);      // round-to-nearest-even
  return (unsigned short)((u + r) >> 16);
}
__device__ __forceinline__ float bf2f(unsigned short h){
  return __uint_as_float(((unsigned)h) << 16);
}
__device__ __forceinline__ f32x16 mfma32(bf16x8 a, bf16x8 b, f32x16 c){
  return __builtin_amdgcn_mfma_f32_32x32x16_bf16(a, b, c, 0, 0, 0);
}
__device__ __forceinline__ f32x16 zero16(){
  f32x16 v;
#pragma unroll
  for (int i = 0; i < 16; ++i) v[i] = 0.f;
  return v;
}

// ---------------------------------------------------------------------------
// prep_pack: build bf16 weight images + int64-detection flag.
// total threads = 131072 + 36864 + 9216 + 2304 = 179456 = 701*256
// ---------------------------------------------------------------------------
__global__ void prep_pack(const float* __restrict__ W1, const float* __restrict__ W2,
                          const float* __restrict__ W3, const float* __restrict__ W4,
                          const int* __restrict__ ei32, char* __restrict__ ws)
{
  int i = blockIdx.x * 256 + threadIdx.x;
  unsigned short* w1i = (unsigned short*)(ws + OFF_W1);
  unsigned short* w2i = (unsigned short*)(ws + OFF_W2);
  unsigned short* w3i = (unsigned short*)(ws + OFF_W3);
  unsigned short* w4i = (unsigned short*)(ws + OFF_W4);

  if (i < 131072){
    // W1ab^T: [out 512][k 256]; out<256 -> W1 rows 0..255 (src), out>=256 -> rows 256..511 (dst)
    int r = i >> 8, k = i & 255;
    float v = (r < 256) ? W1[(size_t)k*256 + r] : W1[(size_t)(256 + k)*256 + (r - 256)];
    w1i[i] = f2bf(v);
  } else if (i < 131072 + 36864){
    int i2 = i - 131072;
    int c = i2 / 9216, rem = i2 % 9216, r = rem / 72, j = rem % 72, k = c*64 + j;
    float v = (j < 64) ? W2[(size_t)k*128 + r] : 0.f;
    w2i[i2] = f2bf(v);
  } else if (i < 131072 + 36864 + 9216){
    int i3 = i - 131072 - 36864;
    int c = i3 / 4608, rem = i3 % 4608, r = rem / 72, j = rem % 72, k = c*64 + j;
    float v = (j < 64) ? W3[(size_t)k*64 + r] : 0.f;
    w3i[i3] = f2bf(v);
  } else if (i < 131072 + 36864 + 9216 + 2304){
    int i4 = i - 131072 - 36864 - 9216;
    int r = i4 / 72, j = i4 % 72;
    float v = (j < 64 && r < 3) ? W4[(size_t)j*3 + r] : 0.f;
    w4i[i4] = f2bf(v);
  }
  if (i < 768){
    // W1c rows 512..514 kept in f32 (attr contribution added pre-relu in f32)
    float* w1c = (float*)(ws + OFF_W1C);
    w1c[i] = W1[(size_t)(512 + i/256)*256 + (i & 255)];
  }
  if (i == 0){
    // int64 edge_index? then every odd int32 word (high half) is 0.
    int f = 1;
    for (int t = 1; t < 64; t += 2) if (ei32[t] != 0) { f = 0; break; }
    *(int*)(ws + OFF_FLAG) = f;
  }
}

// ---------------------------------------------------------------------------
// gemm1: PQ[n][o] = sum_k emb[n][k]*W1ab[k][o]  (+ b1[o] folded for o<256)
// block = 256 thr (4 waves); block covers 64 nodes x 512 outs.
// wave w: outs w*128..+127 (4 A-tiles of 32), nodes = 2 B-groups of 32.
// No LDS: A-frags straight from L2 (each block reads W1 image once).
// ---------------------------------------------------------------------------
__global__ __launch_bounds__(256, 2) void gemm1(const float* __restrict__ emb,
                                                const float* __restrict__ b1,
                                                char* __restrict__ ws)
{
  const int tid = threadIdx.x;
  const int wv = tid >> 6, l = tid & 63, ln = l & 31, g2 = l >> 5;
  const int nb = blockIdx.x * 64;
  const int ob = wv * 128;
  const unsigned short* Wt = (const unsigned short*)(ws + OFF_W1);
  unsigned short* PQ = (unsigned short*)(ws + OFF_PQ);

  int n_[2];
#pragma unroll
  for (int bg = 0; bg < 2; ++bg){
    int n = nb + bg*32 + ln;
    n_[bg] = (n < NN) ? n : (NN - 1);
  }

  f32x16 acc[4][2];
#pragma unroll
  for (int t = 0; t < 4; ++t){ acc[t][0] = zero16(); acc[t][1] = zero16(); }

  // 1-deep software pipeline over 16 k-steps (K=256, 16 per MFMA)
  bf16x8 aN[4]; f32x4 eN[2][2];
#pragma unroll
  for (int t = 0; t < 4; ++t)
    aN[t] = *(const bf16x8*)(Wt + (size_t)(ob + t*32 + ln)*256 + g2*8);
#pragma unroll
  for (int bg = 0; bg < 2; ++bg){
    const f32x4* p = (const f32x4*)(emb + (size_t)n_[bg]*256 + g2*8);
    eN[bg][0] = p[0]; eN[bg][1] = p[1];
  }

#pragma unroll 1
  for (int kq = 0; kq < 16; ++kq){
    bf16x8 aC[4] = {aN[0], aN[1], aN[2], aN[3]};
    f32x4 eC[2][2] = {{eN[0][0], eN[0][1]}, {eN[1][0], eN[1][1]}};
    if (kq < 15){
      int k0 = (kq + 1)*16 + g2*8;
#pragma unroll
      for (int t = 0; t < 4; ++t)
        aN[t] = *(const bf16x8*)(Wt + (size_t)(ob + t*32 + ln)*256 + k0);
#pragma unroll
      for (int bg = 0; bg < 2; ++bg){
        const f32x4* p = (const f32x4*)(emb + (size_t)n_[bg]*256 + k0);
        eN[bg][0] = p[0]; eN[bg][1] = p[1];
      }
    }
#pragma unroll
    for (int bg = 0; bg < 2; ++bg){
      bf16x8 b;
#pragma unroll
      for (int j = 0; j < 4; ++j){
        b[j]     = (short)f2bf(eC[bg][0][j]);
        b[4 + j] = (short)f2bf(eC[bg][1][j]);
      }
#pragma unroll
      for (int t = 0; t < 4; ++t) acc[t][bg] = mfma32(aC[t], b, acc[t][bg]);
    }
  }

  // epilogue: +b1 for o<256 (P half), store bf16. D row = (reg&3)+8*(reg>>2)+4*g2.
#pragma unroll
  for (int t = 0; t < 4; ++t){
    const int obase = ob + t*32;
#pragma unroll
    for (int bg = 0; bg < 2; ++bg){
      int n = nb + bg*32 + ln;
      if (n < NN){
#pragma unroll
        for (int rr = 0; rr < 4; ++rr){
          int o = obase + rr*8 + g2*4;
          f32x4 bv = {0.f, 0.f, 0.f, 0.f};
          if (obase < 256) bv = *(const f32x4*)(b1 + o);
          u16x4 st;
#pragma unroll
          for (int j = 0; j < 4; ++j) st[j] = f2bf(acc[t][bg][rr*4 + j] + bv[j]);
          *(u16x4*)(PQ + (size_t)n*512 + o) = st;
        }
      }
    }
  }
}

// ---------------------------------------------------------------------------
// fused: h1 = relu(P[src]+Q[dst]+attr@W1c) built IN REGISTERS directly in the
// B-fragment layout (lane=edge col, k octet contiguous). L2/L3/L4 via MFMA
// with W chunks staged in LDS. block = 256 thr (4 waves), wave = 64 edges.
// LDS: wslot 18432 (W chunk) + 4 x 9216 per-wave h slots = 55296 B.
// ---------------------------------------------------------------------------
__global__ __launch_bounds__(256, 2) void fused(const int* __restrict__ eidx,
                                                const float* __restrict__ attr,
                                                const float* __restrict__ b2,
                                                const float* __restrict__ b3,
                                                const float* __restrict__ b4,
                                                const char* __restrict__ ws,
                                                float* __restrict__ out)
{
  __shared__ __align__(16) char smem[18432 + 4*9216];
  char* wslot = smem;
  const int tid = threadIdx.x;
  const int wv = tid >> 6, l = tid & 63, ln = l & 31, g2 = l >> 5;
  char* hslot = smem + 18432 + wv*9216;

  const unsigned short* PQ = (const unsigned short*)(ws + OFF_PQ);
  const float* W1c = (const float*)(ws + OFF_W1C);
  const int flag64 = *(const int*)(ws + OFF_FLAG);
  const int eb = blockIdx.x * 256 + wv * 64;

  int si[2], di[2];
  float at0[2], at1[2], at2[2];
#pragma unroll
  for (int bg = 0; bg < 2; ++bg){
    int e = eb + bg*32 + ln;
    bool v = (e < NE);
    int ec = v ? e : 0;
    si[bg] = flag64 ? eidx[2*(size_t)ec]              : eidx[ec];
    di[bg] = flag64 ? eidx[2*((size_t)NE + ec)]       : eidx[NE + ec];
    at0[bg] = v ? attr[(size_t)ec*3 + 0] : 0.f;
    at1[bg] = v ? attr[(size_t)ec*3 + 1] : 0.f;
    at2[bg] = v ? attr[(size_t)ec*3 + 2] : 0.f;
  }

  // ---------------- Layer 2: h2 = h1 @ W2 + b2 (no relu), K=256 ------------
  f32x16 acc2[4][2];
#pragma unroll
  for (int t = 0; t < 4; ++t){ acc2[t][0] = zero16(); acc2[t][1] = zero16(); }

  bf16x8 pN[2], qN[2];
  {
    int k0 = g2*8;
#pragma unroll
    for (int bg = 0; bg < 2; ++bg){
      pN[bg] = *(const bf16x8*)(PQ + (size_t)si[bg]*512 + k0);
      qN[bg] = *(const bf16x8*)(PQ + (size_t)di[bg]*512 + 256 + k0);
    }
  }

#pragma unroll 1
  for (int s = 0; s < 16; ++s){
    const int c = s >> 2, kq = s & 3;
    if (kq == 0){
      __syncthreads();
      const uint4* src = (const uint4*)(ws + OFF_W2 + (size_t)c*18432);
      uint4* dst = (uint4*)wslot;
      for (int i = tid; i < 1152; i += 256) dst[i] = src[i];
      __syncthreads();
    }
    bf16x8 pC[2] = {pN[0], pN[1]}, qC[2] = {qN[0], qN[1]};
    if (s < 15){
      int k0n = ((s + 1) >> 2)*64 + ((s + 1) & 3)*16 + g2*8;
#pragma unroll
      for (int bg = 0; bg < 2; ++bg){
        pN[bg] = *(const bf16x8*)(PQ + (size_t)si[bg]*512 + k0n);
        qN[bg] = *(const bf16x8*)(PQ + (size_t)di[bg]*512 + 256 + k0n);
      }
    }
    const int k0 = c*64 + kq*16 + g2*8;
    float wc[3][8];
#pragma unroll
    for (int m = 0; m < 3; ++m){
      f32x4 w0 = *(const f32x4*)(W1c + m*256 + k0);
      f32x4 w1 = *(const f32x4*)(W1c + m*256 + k0 + 4);
#pragma unroll
      for (int j = 0; j < 4; ++j){ wc[m][j] = w0[j]; wc[m][4 + j] = w1[j]; }
    }
    bf16x8 b[2];
#pragma unroll
    for (int bg = 0; bg < 2; ++bg){
#pragma unroll
      for (int j = 0; j < 8; ++j){
        float h = bf2f((unsigned short)pC[bg][j]) + bf2f((unsigned short)qC[bg][j])
                + at0[bg]*wc[0][j] + at1[bg]*wc[1][j] + at2[bg]*wc[2][j];
        b[bg][j] = (short)f2bf(fmaxf(h, 0.f));
      }
    }
#pragma unroll
    for (int t = 0; t < 4; ++t){
      bf16x8 af = *(const bf16x8*)(wslot + (size_t)(t*32 + ln)*144 + (size_t)(kq*16 + g2*8)*2);
      acc2[t][0] = mfma32(af, b[0], acc2[t][0]);
      acc2[t][1] = mfma32(af, b[1], acc2[t][1]);
    }
  }

  // ------------- Layer 3: h3 = relu(h2 @ W3 + b3), K=128, 2 passes ---------
  f32x16 acc3[2][2];
  acc3[0][0] = zero16(); acc3[0][1] = zero16();
  acc3[1][0] = zero16(); acc3[1][1] = zero16();

#pragma unroll 1
  for (int p = 0; p < 2; ++p){
    __syncthreads();
    {
      const uint4* src = (const uint4*)(ws + OFF_W3 + (size_t)p*9216);
      uint4* dst = (uint4*)wslot;
      for (int i = tid; i < 576; i += 256) dst[i] = src[i];
    }
    __syncthreads();
    // write h2 pass p (feats 64p..64p+63) into per-wave slot (bf16, +b2, no relu)
#pragma unroll
    for (int th = 0; th < 2; ++th){
      int t = 2*p + th;
#pragma unroll
      for (int bg = 0; bg < 2; ++bg){
#pragma unroll
        for (int rr = 0; rr < 4; ++rr){
          int fg = t*32 + rr*8 + g2*4;
          f32x4 bv = *(const f32x4*)(b2 + fg);
          u16x4 st;
#pragma unroll
          for (int j = 0; j < 4; ++j) st[j] = f2bf(acc2[t][bg][rr*4 + j] + bv[j]);
          *(u16x4*)(hslot + (size_t)(bg*32 + ln)*144 + (size_t)(th*32 + rr*8 + g2*4)*2) = st;
        }
      }
    }
#pragma unroll
    for (int kq = 0; kq < 4; ++kq){
      bf16x8 bb[2];
#pragma unroll
      for (int bg = 0; bg < 2; ++bg)
        bb[bg] = *(const bf16x8*)(hslot + (size_t)(bg*32 + ln)*144 + (size_t)(kq*16 + g2*8)*2);
#pragma unroll
      for (int t2 = 0; t2 < 2; ++t2){
        bf16x8 af = *(const bf16x8*)(wslot + (size_t)(t2*32 + ln)*144 + (size_t)(kq*16 + g2*8)*2);
        acc3[t2][0] = mfma32(af, bb[0], acc3[t2][0]);
        acc3[t2][1] = mfma32(af, bb[1], acc3[t2][1]);
      }
    }
  }

  // h3 -> slot (relu)
#pragma unroll
  for (int t = 0; t < 2; ++t){
#pragma unroll
    for (int bg = 0; bg < 2; ++bg){
#pragma unroll
      for (int rr = 0; rr < 4; ++rr){
        int fg = t*32 + rr*8 + g2*4;
        f32x4 bv = *(const f32x4*)(b3 + fg);
        u16x4 st;
#pragma unroll
        for (int j = 0; j < 4; ++j) st[j] = f2bf(fmaxf(acc3[t][bg][rr*4 + j] + bv[j], 0.f));
        *(u16x4*)(hslot + (size_t)(bg*32 + ln)*144 + (size_t)fg*2) = st;
      }
    }
  }

  // ---------------- Layer 4: logits = h3 @ W4 + b4, K=64, outs 3 -----------
  __syncthreads();
  {
    const uint4* src = (const uint4*)(ws + OFF_W4);
    uint4* dst = (uint4*)wslot;
    for (int i = tid; i < 288; i += 256) dst[i] = src[i];
  }
  __syncthreads();

  f32x16 acc4[2];
  acc4[0] = zero16(); acc4[1] = zero16();
#pragma unroll
  for (int kq = 0; kq < 4; ++kq){
    bf16x8 af = *(const bf16x8*)(wslot + (size_t)ln*144 + (size_t)(kq*16 + g2*8)*2);
#pragma unroll
    for (int bg = 0; bg < 2; ++bg){
      bf16x8 bb = *(const bf16x8*)(hslot + (size_t)(bg*32 + ln)*144 + (size_t)(kq*16 + g2*8)*2);
      acc4[bg] = mfma32(af, bb, acc4[bg]);
    }
  }
  if (g2 == 0){
    float c0 = b4[0], c1 = b4[1], c2 = b4[2];
#pragma unroll
    for (int bg = 0; bg < 2; ++bg){
      int e = eb + bg*32 + ln;
      if (e < NE){
        out[(size_t)e*3 + 0] = acc4[bg][0] + c0;   // D rows 0..2 for g2==0, reg 0..2
        out[(size_t)e*3 + 1] = acc4[bg][1] + c1;
        out[(size_t)e*3 + 2] = acc4[bg][2] + c2;
      }
    }
  }
}

// ---------------------------------------------------------------------------
extern "C" void kernel_launch(void* const* d_in, const int* in_sizes, int n_in,
                              void* d_out, int out_size, void* d_ws, size_t ws_size,
                              hipStream_t stream)
{
  const float* emb  = (const float*)d_in[0];
  const int*   eidx = (const int*)  d_in[1];
  const float* attr = (const float*)d_in[2];
  const float* W1   = (const float*)d_in[3];
  const float* b1   = (const float*)d_in[4];
  const float* W2   = (const float*)d_in[5];
  const float* b2   = (const float*)d_in[6];
  const float* W3   = (const float*)d_in[7];
  const float* b3   = (const float*)d_in[8];
  const float* W4   = (const float*)d_in[9];
  const float* b4   = (const float*)d_in[10];
  char* ws = (char*)d_ws;
  float* out = (float*)d_out;

  if (ws_size < WS_NEED) return;  // scratch too small: bail cleanly (validation will flag)

  prep_pack<<<701, 256, 0, stream>>>(W1, W2, W3, W4, eidx, ws);
  gemm1<<<(NN + 63)/64, 256, 0, stream>>>(emb, b1, ws);
  fused<<<(NE + 255)/256, 256, 0, stream>>>(eidx, attr, b2, b3, b4, ws, out);
}

// Round 2
// 204.817 us; speedup vs baseline: 3.2051x; 3.2051x over previous
//
#include <hip/hip_runtime.h>
#include <hip/hip_bf16.h>
#include <stdint.h>
#include <stddef.h>

// ---------------------------------------------------------------------------
// InteractionPredictionHead: edge MLP over a graph.
//   logits[e] = relu(relu([src|dst|attr]@W1+b1)@W2+b2 ... ) per reference.
// Key algebraic rewrite: feats@W1 = P[src] + Q[dst] + attr@W1c + b1, with
//   P = emb@W1[0:256,:], Q = emb@W1[256:512,:]  (per-NODE, 50k rows not 300k)
// Kernels: prep_pack (weight bf16 images into ws), gemm1 (PQ), fused (rest).
// MFMA: v_mfma_f32_32x32x16_bf16, swapped operands (D = W^T * act^T).
// R1 fix: layer-3 pass loop had RUNTIME p indexing acc2[2*p+th] -> whole
//   acc2 array demoted to scratch (rule #20), 2.5 GB HBM writes. Now the two
//   passes are macro-expanded with literal P so all acc indices are static.
// ---------------------------------------------------------------------------

#define NN 50000
#define NE 300000

using bf16x8 = __attribute__((ext_vector_type(8))) short;
using f32x16 = __attribute__((ext_vector_type(16))) float;
using f32x4  = __attribute__((ext_vector_type(4))) float;
using u16x4  = __attribute__((ext_vector_type(4))) unsigned short;

// ---- ws layout (bytes, all 16B aligned) ----
#define OFF_PQ   0ULL
#define SZ_PQ    (50000ULL*512ULL*2ULL)          // PQ bf16 [n][512]  (51.2 MB)
#define OFF_W1   (OFF_PQ + SZ_PQ)                // W1ab^T bf16 [512 out][256 k]
#define SZ_W1    (512ULL*256ULL*2ULL)
#define OFF_W1C  (OFF_W1 + SZ_W1)                // W1c f32 [3][256]
#define SZ_W1C   (3ULL*256ULL*4ULL)
#define OFF_W2   (OFF_W1C + SZ_W1C)              // 4 chunks [128 out][72 k] bf16
#define SZ_W2    (4ULL*128ULL*72ULL*2ULL)
#define OFF_W3   (OFF_W2 + SZ_W2)                // 2 chunks [64][72]
#define SZ_W3    (2ULL*64ULL*72ULL*2ULL)
#define OFF_W4   (OFF_W3 + SZ_W3)                // 1 chunk [32][72]
#define SZ_W4    (32ULL*72ULL*2ULL)
#define OFF_FLAG (OFF_W4 + SZ_W4)
#define WS_NEED  (OFF_FLAG + 16ULL)

__device__ __forceinline__ unsigned short f2bf(float x){
  unsigned u = __float_as_uint(x);
  unsigned r = 0x7FFFu + ((u >> 16) & 1u);      // round-to-nearest-even
  return (unsigned short)((u + r) >> 16);
}
__device__ __forceinline__ float bf2f(unsigned short h){
  return __uint_as_float(((unsigned)h) << 16);
}
__device__ __forceinline__ f32x16 mfma32(bf16x8 a, bf16x8 b, f32x16 c){
  return __builtin_amdgcn_mfma_f32_32x32x16_bf16(a, b, c, 0, 0, 0);
}
__device__ __forceinline__ f32x16 zero16(){
  f32x16 v;
#pragma unroll
  for (int i = 0; i < 16; ++i) v[i] = 0.f;
  return v;
}

// ---------------------------------------------------------------------------
// prep_pack: build bf16 weight images + int64-detection flag.
// total threads = 131072 + 36864 + 9216 + 2304 = 179456 = 701*256
// ---------------------------------------------------------------------------
__global__ void prep_pack(const float* __restrict__ W1, const float* __restrict__ W2,
                          const float* __restrict__ W3, const float* __restrict__ W4,
                          const int* __restrict__ ei32, char* __restrict__ ws)
{
  int i = blockIdx.x * 256 + threadIdx.x;
  unsigned short* w1i = (unsigned short*)(ws + OFF_W1);
  unsigned short* w2i = (unsigned short*)(ws + OFF_W2);
  unsigned short* w3i = (unsigned short*)(ws + OFF_W3);
  unsigned short* w4i = (unsigned short*)(ws + OFF_W4);

  if (i < 131072){
    int r = i >> 8, k = i & 255;
    float v = (r < 256) ? W1[(size_t)k*256 + r] : W1[(size_t)(256 + k)*256 + (r - 256)];
    w1i[i] = f2bf(v);
  } else if (i < 131072 + 36864){
    int i2 = i - 131072;
    int c = i2 / 9216, rem = i2 % 9216, r = rem / 72, j = rem % 72, k = c*64 + j;
    float v = (j < 64) ? W2[(size_t)k*128 + r] : 0.f;
    w2i[i2] = f2bf(v);
  } else if (i < 131072 + 36864 + 9216){
    int i3 = i - 131072 - 36864;
    int c = i3 / 4608, rem = i3 % 4608, r = rem / 72, j = rem % 72, k = c*64 + j;
    float v = (j < 64) ? W3[(size_t)k*64 + r] : 0.f;
    w3i[i3] = f2bf(v);
  } else if (i < 131072 + 36864 + 9216 + 2304){
    int i4 = i - 131072 - 36864 - 9216;
    int r = i4 / 72, j = i4 % 72;
    float v = (j < 64 && r < 3) ? W4[(size_t)j*3 + r] : 0.f;
    w4i[i4] = f2bf(v);
  }
  if (i < 768){
    float* w1c = (float*)(ws + OFF_W1C);
    w1c[i] = W1[(size_t)(512 + i/256)*256 + (i & 255)];
  }
  if (i == 0){
    int f = 1;
    for (int t = 1; t < 64; t += 2) if (ei32[t] != 0) { f = 0; break; }
    *(int*)(ws + OFF_FLAG) = f;
  }
}

// ---------------------------------------------------------------------------
// gemm1: PQ[n][o] = sum_k emb[n][k]*W1ab[k][o]  (+ b1[o] folded for o<256)
// ---------------------------------------------------------------------------
__global__ __launch_bounds__(256, 2) void gemm1(const float* __restrict__ emb,
                                                const float* __restrict__ b1,
                                                char* __restrict__ ws)
{
  const int tid = threadIdx.x;
  const int wv = tid >> 6, l = tid & 63, ln = l & 31, g2 = l >> 5;
  const int nb = blockIdx.x * 64;
  const int ob = wv * 128;
  const unsigned short* Wt = (const unsigned short*)(ws + OFF_W1);
  unsigned short* PQ = (unsigned short*)(ws + OFF_PQ);

  int n_[2];
#pragma unroll
  for (int bg = 0; bg < 2; ++bg){
    int n = nb + bg*32 + ln;
    n_[bg] = (n < NN) ? n : (NN - 1);
  }

  f32x16 acc[4][2];
#pragma unroll
  for (int t = 0; t < 4; ++t){ acc[t][0] = zero16(); acc[t][1] = zero16(); }

  bf16x8 aN[4]; f32x4 eN[2][2];
#pragma unroll
  for (int t = 0; t < 4; ++t)
    aN[t] = *(const bf16x8*)(Wt + (size_t)(ob + t*32 + ln)*256 + g2*8);
#pragma unroll
  for (int bg = 0; bg < 2; ++bg){
    const f32x4* p = (const f32x4*)(emb + (size_t)n_[bg]*256 + g2*8);
    eN[bg][0] = p[0]; eN[bg][1] = p[1];
  }

#pragma unroll 1
  for (int kq = 0; kq < 16; ++kq){
    bf16x8 aC[4] = {aN[0], aN[1], aN[2], aN[3]};
    f32x4 eC[2][2] = {{eN[0][0], eN[0][1]}, {eN[1][0], eN[1][1]}};
    if (kq < 15){
      int k0 = (kq + 1)*16 + g2*8;
#pragma unroll
      for (int t = 0; t < 4; ++t)
        aN[t] = *(const bf16x8*)(Wt + (size_t)(ob + t*32 + ln)*256 + k0);
#pragma unroll
      for (int bg = 0; bg < 2; ++bg){
        const f32x4* p = (const f32x4*)(emb + (size_t)n_[bg]*256 + k0);
        eN[bg][0] = p[0]; eN[bg][1] = p[1];
      }
    }
#pragma unroll
    for (int bg = 0; bg < 2; ++bg){
      bf16x8 b;
#pragma unroll
      for (int j = 0; j < 4; ++j){
        b[j]     = (short)f2bf(eC[bg][0][j]);
        b[4 + j] = (short)f2bf(eC[bg][1][j]);
      }
#pragma unroll
      for (int t = 0; t < 4; ++t) acc[t][bg] = mfma32(aC[t], b, acc[t][bg]);
    }
  }

#pragma unroll
  for (int t = 0; t < 4; ++t){
    const int obase = ob + t*32;
#pragma unroll
    for (int bg = 0; bg < 2; ++bg){
      int n = nb + bg*32 + ln;
      if (n < NN){
#pragma unroll
        for (int rr = 0; rr < 4; ++rr){
          int o = obase + rr*8 + g2*4;
          f32x4 bv = {0.f, 0.f, 0.f, 0.f};
          if (obase < 256) bv = *(const f32x4*)(b1 + o);
          u16x4 st;
#pragma unroll
          for (int j = 0; j < 4; ++j) st[j] = f2bf(acc[t][bg][rr*4 + j] + bv[j]);
          *(u16x4*)(PQ + (size_t)n*512 + o) = st;
        }
      }
    }
  }
}

// ---------------------------------------------------------------------------
// fused: h1 = relu(P[src]+Q[dst]+attr@W1c) built IN REGISTERS in B-frag
// layout; L2/L3/L4 via MFMA with W chunks staged in LDS.
// block = 256 thr (4 waves), wave = 64 edges.
// ---------------------------------------------------------------------------

// Layer-3 pass with COMPILE-TIME literal P (so acc2[2*P+th] indices are
// static -> acc arrays stay in registers; runtime p was demoting acc2 to
// scratch = 2.5 GB HBM writes).
#define LAYER3_PASS(P)                                                          \
  do {                                                                          \
    __syncthreads();                                                            \
    {                                                                           \
      const uint4* src3 = (const uint4*)(ws + OFF_W3 + (size_t)(P)*9216);       \
      uint4* dst3 = (uint4*)wslot;                                              \
      for (int i = tid; i < 576; i += 256) dst3[i] = src3[i];                   \
    }                                                                           \
    __syncthreads();                                                            \
    _Pragma("unroll")                                                           \
    for (int th = 0; th < 2; ++th){                                             \
      _Pragma("unroll")                                                         \
      for (int bg = 0; bg < 2; ++bg){                                           \
        _Pragma("unroll")                                                       \
        for (int rr = 0; rr < 4; ++rr){                                         \
          int fg = (2*(P) + th)*32 + rr*8 + g2*4;                               \
          f32x4 bv = *(const f32x4*)(b2 + fg);                                  \
          u16x4 st;                                                             \
          _Pragma("unroll")                                                     \
          for (int j = 0; j < 4; ++j)                                           \
            st[j] = f2bf(acc2[2*(P) + th][bg][rr*4 + j] + bv[j]);               \
          *(u16x4*)(hslot + (size_t)(bg*32 + ln)*144                            \
                          + (size_t)(th*32 + rr*8 + g2*4)*2) = st;              \
        }                                                                       \
      }                                                                         \
    }                                                                           \
    _Pragma("unroll")                                                           \
    for (int kq = 0; kq < 4; ++kq){                                             \
      bf16x8 bb[2];                                                             \
      _Pragma("unroll")                                                         \
      for (int bg = 0; bg < 2; ++bg)                                            \
        bb[bg] = *(const bf16x8*)(hslot + (size_t)(bg*32 + ln)*144              \
                                        + (size_t)(kq*16 + g2*8)*2);            \
      _Pragma("unroll")                                                         \
      for (int t2 = 0; t2 < 2; ++t2){                                           \
        bf16x8 af = *(const bf16x8*)(wslot + (size_t)(t2*32 + ln)*144           \
                                           + (size_t)(kq*16 + g2*8)*2);         \
        acc3[t2][0] = mfma32(af, bb[0], acc3[t2][0]);                           \
        acc3[t2][1] = mfma32(af, bb[1], acc3[t2][1]);                           \
      }                                                                         \
    }                                                                           \
  } while (0)

__global__ __launch_bounds__(256, 2) void fused(const int* __restrict__ eidx,
                                                const float* __restrict__ attr,
                                                const float* __restrict__ b2,
                                                const float* __restrict__ b3,
                                                const float* __restrict__ b4,
                                                const char* __restrict__ ws,
                                                float* __restrict__ out)
{
  __shared__ __align__(16) char smem[18432 + 4*9216];
  char* wslot = smem;
  const int tid = threadIdx.x;
  const int wv = tid >> 6, l = tid & 63, ln = l & 31, g2 = l >> 5;
  char* hslot = smem + 18432 + wv*9216;

  const unsigned short* PQ = (const unsigned short*)(ws + OFF_PQ);
  const float* W1c = (const float*)(ws + OFF_W1C);
  const int flag64 = *(const int*)(ws + OFF_FLAG);
  const int eb = blockIdx.x * 256 + wv * 64;

  int si[2], di[2];
  float at0[2], at1[2], at2[2];
#pragma unroll
  for (int bg = 0; bg < 2; ++bg){
    int e = eb + bg*32 + ln;
    bool v = (e < NE);
    int ec = v ? e : 0;
    si[bg] = flag64 ? eidx[2*(size_t)ec]              : eidx[ec];
    di[bg] = flag64 ? eidx[2*((size_t)NE + ec)]       : eidx[NE + ec];
    at0[bg] = v ? attr[(size_t)ec*3 + 0] : 0.f;
    at1[bg] = v ? attr[(size_t)ec*3 + 1] : 0.f;
    at2[bg] = v ? attr[(size_t)ec*3 + 2] : 0.f;
  }

  // ---------------- Layer 2: h2 = h1 @ W2 + b2 (no relu), K=256 ------------
  f32x16 acc2[4][2];
#pragma unroll
  for (int t = 0; t < 4; ++t){ acc2[t][0] = zero16(); acc2[t][1] = zero16(); }

  bf16x8 pN[2], qN[2];
  {
    int k0 = g2*8;
#pragma unroll
    for (int bg = 0; bg < 2; ++bg){
      pN[bg] = *(const bf16x8*)(PQ + (size_t)si[bg]*512 + k0);
      qN[bg] = *(const bf16x8*)(PQ + (size_t)di[bg]*512 + 256 + k0);
    }
  }

#pragma unroll 1
  for (int s = 0; s < 16; ++s){
    const int c = s >> 2, kq = s & 3;
    if (kq == 0){
      __syncthreads();
      const uint4* src = (const uint4*)(ws + OFF_W2 + (size_t)c*18432);
      uint4* dst = (uint4*)wslot;
      for (int i = tid; i < 1152; i += 256) dst[i] = src[i];
      __syncthreads();
    }
    bf16x8 pC[2] = {pN[0], pN[1]}, qC[2] = {qN[0], qN[1]};
    if (s < 15){
      int k0n = ((s + 1) >> 2)*64 + ((s + 1) & 3)*16 + g2*8;
#pragma unroll
      for (int bg = 0; bg < 2; ++bg){
        pN[bg] = *(const bf16x8*)(PQ + (size_t)si[bg]*512 + k0n);
        qN[bg] = *(const bf16x8*)(PQ + (size_t)di[bg]*512 + 256 + k0n);
      }
    }
    const int k0 = c*64 + kq*16 + g2*8;
    float wc[3][8];
#pragma unroll
    for (int m = 0; m < 3; ++m){
      f32x4 w0 = *(const f32x4*)(W1c + m*256 + k0);
      f32x4 w1 = *(const f32x4*)(W1c + m*256 + k0 + 4);
#pragma unroll
      for (int j = 0; j < 4; ++j){ wc[m][j] = w0[j]; wc[m][4 + j] = w1[j]; }
    }
    bf16x8 b[2];
#pragma unroll
    for (int bg = 0; bg < 2; ++bg){
#pragma unroll
      for (int j = 0; j < 8; ++j){
        float h = bf2f((unsigned short)pC[bg][j]) + bf2f((unsigned short)qC[bg][j])
                + at0[bg]*wc[0][j] + at1[bg]*wc[1][j] + at2[bg]*wc[2][j];
        b[bg][j] = (short)f2bf(fmaxf(h, 0.f));
      }
    }
#pragma unroll
    for (int t = 0; t < 4; ++t){
      bf16x8 af = *(const bf16x8*)(wslot + (size_t)(t*32 + ln)*144 + (size_t)(kq*16 + g2*8)*2);
      acc2[t][0] = mfma32(af, b[0], acc2[t][0]);
      acc2[t][1] = mfma32(af, b[1], acc2[t][1]);
    }
  }

  // ------------- Layer 3: h3 = relu(h2 @ W3 + b3), K=128, 2 passes ---------
  f32x16 acc3[2][2];
  acc3[0][0] = zero16(); acc3[0][1] = zero16();
  acc3[1][0] = zero16(); acc3[1][1] = zero16();

  LAYER3_PASS(0);
  LAYER3_PASS(1);

  // h3 -> slot (relu)
#pragma unroll
  for (int t = 0; t < 2; ++t){
#pragma unroll
    for (int bg = 0; bg < 2; ++bg){
#pragma unroll
      for (int rr = 0; rr < 4; ++rr){
        int fg = t*32 + rr*8 + g2*4;
        f32x4 bv = *(const f32x4*)(b3 + fg);
        u16x4 st;
#pragma unroll
        for (int j = 0; j < 4; ++j) st[j] = f2bf(fmaxf(acc3[t][bg][rr*4 + j] + bv[j], 0.f));
        *(u16x4*)(hslot + (size_t)(bg*32 + ln)*144 + (size_t)fg*2) = st;
      }
    }
  }

  // ---------------- Layer 4: logits = h3 @ W4 + b4, K=64, outs 3 -----------
  __syncthreads();
  {
    const uint4* src = (const uint4*)(ws + OFF_W4);
    uint4* dst = (uint4*)wslot;
    for (int i = tid; i < 288; i += 256) dst[i] = src[i];
  }
  __syncthreads();

  f32x16 acc4[2];
  acc4[0] = zero16(); acc4[1] = zero16();
#pragma unroll
  for (int kq = 0; kq < 4; ++kq){
    bf16x8 af = *(const bf16x8*)(wslot + (size_t)ln*144 + (size_t)(kq*16 + g2*8)*2);
#pragma unroll
    for (int bg = 0; bg < 2; ++bg){
      bf16x8 bb = *(const bf16x8*)(hslot + (size_t)(bg*32 + ln)*144 + (size_t)(kq*16 + g2*8)*2);
      acc4[bg] = mfma32(af, bb, acc4[bg]);
    }
  }
  if (g2 == 0){
    float c0 = b4[0], c1 = b4[1], c2 = b4[2];
#pragma unroll
    for (int bg = 0; bg < 2; ++bg){
      int e = eb + bg*32 + ln;
      if (e < NE){
        out[(size_t)e*3 + 0] = acc4[bg][0] + c0;
        out[(size_t)e*3 + 1] = acc4[bg][1] + c1;
        out[(size_t)e*3 + 2] = acc4[bg][2] + c2;
      }
    }
  }
}

// ---------------------------------------------------------------------------
extern "C" void kernel_launch(void* const* d_in, const int* in_sizes, int n_in,
                              void* d_out, int out_size, void* d_ws, size_t ws_size,
                              hipStream_t stream)
{
  const float* emb  = (const float*)d_in[0];
  const int*   eidx = (const int*)  d_in[1];
  const float* attr = (const float*)d_in[2];
  const float* W1   = (const float*)d_in[3];
  const float* b1   = (const float*)d_in[4];
  const float* W2   = (const float*)d_in[5];
  const float* b2   = (const float*)d_in[6];
  const float* W3   = (const float*)d_in[7];
  const float* b3   = (const float*)d_in[8];
  const float* W4   = (const float*)d_in[9];
  const float* b4   = (const float*)d_in[10];
  char* ws = (char*)d_ws;
  float* out = (float*)d_out;

  if (ws_size < WS_NEED) return;

  prep_pack<<<701, 256, 0, stream>>>(W1, W2, W3, W4, eidx, ws);
  gemm1<<<(NN + 63)/64, 256, 0, stream>>>(emb, b1, ws);
  fused<<<(NE + 255)/256, 256, 0, stream>>>(eidx, attr, b2, b3, b4, ws, out);
}